// Round 10
// baseline (121.319 us; speedup 1.0000x reference)
//
#include <hip/hip_runtime.h>
#include <hip/hip_bf16.h>
#include <stdint.h>

#define NB 256
#define LQ 128
#define LC 512
#define DIM 384
#define CBP 392     // bf16 tile pitch in shorts (784 B)
#define NST 12      // 4 q tiles + 8 c tiles (half of LC), 32 rows each

typedef __attribute__((ext_vector_type(8))) short short8;
typedef __attribute__((ext_vector_type(4))) float f4;
typedef __attribute__((ext_vector_type(2))) unsigned int u32x2;

__device__ __forceinline__ unsigned int pk2bf(float a, float b) {
  union { float f; uint32_t u; } x, y; x.f = a; y.f = b;
  uint32_t lo = (x.u + 0x7fffu + ((x.u >> 16) & 1u)) >> 16;
  uint32_t hi = (y.u + 0x7fffu + ((y.u >> 16) & 1u)) >> 16;
  return lo | (hi << 16);
}

// ====================== fused single-pass, c-split ===========================
// Grid 512: (b = bid>>1, c-half = bid&1), 8 waves, 2 blocks/CU.
// Structure identical to round-9 fused2 (2-deep register prefetch, counted
// vmcnt(6), one barrier/stage, raw-bf16 MFMA with qi*ci fold) but 12 stages:
// per-half row-max + pooled partials go to ws, merged by merge_mlp.
__global__ __launch_bounds__(512, 2)
void fused3(const float* __restrict__ qtok, const float* __restrict__ ctok,
            const int* __restrict__ qm, const int* __restrict__ cm,
            float* __restrict__ ws_rm, float* __restrict__ pp_q,
            float* __restrict__ pp_c, float* __restrict__ nn_q,
            float* __restrict__ nn_c) {
  __shared__ unsigned short s_cb[2][32][CBP];  // 50176 B (epilogue: f32 arena)
  __shared__ float s_qi[LQ];
  __shared__ float s_ci[2][32];
  __shared__ int s_qm[LQ];
  __shared__ int s_cm[256];
  __shared__ float s_cnt[16];

  const int bid = blockIdx.x, tid = threadIdx.x;
  const int b = bid >> 1, half = bid & 1;
  const int wave = tid >> 6, lane = tid & 63;
  const int rA = lane & 15, hi = lane >> 4;
  const bool hiHalf = lane >= 32;
  const int l31 = lane & 31;

  const float* qb = qtok + (size_t)b * LQ * DIM;
  const float* cbh = ctok + (size_t)b * LC * DIM + (size_t)half * 256 * DIM;

  if (tid < 256) s_cm[tid] = cm[b * LC + half * 256 + tid];
  if (tid < LQ) s_qm[tid] = qm[b * LQ + tid];
  __syncthreads();

  f4 v0[4], h0[2], v1[4], h1[2];
  f4 pqA = {0,0,0,0}, pqB = {0,0,0,0}, pcA = {0,0,0,0}, pcB = {0,0,0,0};
  float cq = 0.f, cc = 0.f;
  float rm[4] = {-1e9f, -1e9f, -1e9f, -1e9f};
  short8 A[12] = {};

#define TBASE(t) (((t) < 4) ? (qb + (size_t)(t) * 32 * DIM) \
                            : (cbh + (size_t)((t) - 4) * 32 * DIM))

#define ISSUE(V, H, base_) do {                                              \
    const float* bb_ = (base_);                                              \
    _Pragma("unroll")                                                        \
    for (int i_ = 0; i_ < 4; ++i_)                                           \
      V[i_] = *((const f4*)(bb_ + (size_t)(wave * 4 + i_) * DIM) + lane);    \
    _Pragma("unroll")                                                        \
    for (int j_ = 0; j_ < 2; ++j_)                                           \
      H[j_] = *((const f4*)(bb_ + (size_t)(wave * 4 + 2 * j_ +               \
                (hiHalf ? 1 : 0)) * DIM) + 64 + l31);                        \
  } while (0)

#define STAGE(T, V, H, BUF) do {                                             \
    const int t_ = (T);                                                      \
    if (t_ == NST - 1) { asm volatile("s_waitcnt vmcnt(0)" ::: "memory"); }  \
    else               { asm volatile("s_waitcnt vmcnt(6)" ::: "memory"); }  \
    __builtin_amdgcn_sched_barrier(0);                                       \
    const bool isq_ = t_ < 4;                                                \
    const int* mk_ = isq_ ? (s_qm + t_ * 32) : (s_cm + (t_ - 4) * 32);       \
    float ss_[4];                                                            \
    _Pragma("unroll")                                                        \
    for (int i_ = 0; i_ < 4; ++i_) {                                         \
      const int lr_ = wave * 4 + i_;                                         \
      u32x2 w_; w_[0] = pk2bf(V[i_].x, V[i_].y); w_[1] = pk2bf(V[i_].z, V[i_].w); \
      *(u32x2*)&s_cb[BUF][lr_][4 * lane] = w_;                               \
      ss_[i_] = V[i_].x * V[i_].x + V[i_].y * V[i_].y                        \
              + V[i_].z * V[i_].z + V[i_].w * V[i_].w;                       \
    }                                                                        \
    _Pragma("unroll")                                                        \
    for (int j_ = 0; j_ < 2; ++j_) {                                         \
      const int lr_ = wave * 4 + 2 * j_ + (hiHalf ? 1 : 0);                  \
      u32x2 w_; w_[0] = pk2bf(H[j_].x, H[j_].y); w_[1] = pk2bf(H[j_].z, H[j_].w); \
      *(u32x2*)&s_cb[BUF][lr_][256 + 4 * l31] = w_;                          \
      const float td_ = H[j_].x * H[j_].x + H[j_].y * H[j_].y               \
                      + H[j_].z * H[j_].z + H[j_].w * H[j_].w;              \
      if (hiHalf) ss_[2 * j_ + 1] += td_; else ss_[2 * j_] += td_;           \
    }                                                                        \
    _Pragma("unroll")                                                        \
    for (int o_ = 32; o_; o_ >>= 1) {                                        \
      _Pragma("unroll")                                                      \
      for (int i_ = 0; i_ < 4; ++i_) ss_[i_] += __shfl_xor(ss_[i_], o_);     \
    }                                                                        \
    float fm_[4];                                                            \
    _Pragma("unroll")                                                        \
    for (int i_ = 0; i_ < 4; ++i_) fm_[i_] = (float)mk_[wave * 4 + i_];      \
    if (isq_) {                                                              \
      _Pragma("unroll")                                                      \
      for (int i_ = 0; i_ < 4; ++i_) { pqA += V[i_] * fm_[i_]; cq += fm_[i_]; } \
      _Pragma("unroll")                                                      \
      for (int j_ = 0; j_ < 2; ++j_)                                         \
        pqB += H[j_] * (hiHalf ? fm_[2 * j_ + 1] : fm_[2 * j_]);             \
      if (lane == 0) {                                                       \
        _Pragma("unroll")                                                    \
        for (int i_ = 0; i_ < 4; ++i_)                                       \
          s_qi[t_ * 32 + wave * 4 + i_] = 1.0f / fmaxf(sqrtf(ss_[i_]), 1e-12f); \
      }                                                                      \
    } else {                                                                 \
      _Pragma("unroll")                                                      \
      for (int i_ = 0; i_ < 4; ++i_) { pcA += V[i_] * fm_[i_]; cc += fm_[i_]; } \
      _Pragma("unroll")                                                      \
      for (int j_ = 0; j_ < 2; ++j_)                                         \
        pcB += H[j_] * (hiHalf ? fm_[2 * j_ + 1] : fm_[2 * j_]);             \
      if (lane == 0) {                                                       \
        _Pragma("unroll")                                                    \
        for (int i_ = 0; i_ < 4; ++i_)                                       \
          s_ci[BUF][wave * 4 + i_] = 1.0f / fmaxf(sqrtf(ss_[i_]), 1e-12f);   \
      }                                                                      \
    }                                                                        \
    if (t_ + 2 < NST) { ISSUE(V, H, TBASE(t_ + 2)); }                        \
    asm volatile("s_waitcnt lgkmcnt(0)" ::: "memory");                       \
    __builtin_amdgcn_s_barrier();                                            \
    __builtin_amdgcn_sched_barrier(0);                                       \
    if (isq_) {                                                              \
      if ((wave >> 1) == t_) {                                               \
        const int lb_ = (wave & 1) * 16 + rA;                                \
        _Pragma("unroll")                                                    \
        for (int kk_ = 0; kk_ < 12; ++kk_)                                   \
          A[kk_] = *(const short8*)&s_cb[BUF][lb_][kk_ * 32 + hi * 8];       \
        asm volatile("s_waitcnt lgkmcnt(0)" ::: "memory");                   \
        __builtin_amdgcn_sched_barrier(0);                                   \
      }                                                                      \
    } else {                                                                 \
      f4 a0_ = {0,0,0,0}, a1_ = {0,0,0,0};                                   \
      _Pragma("unroll")                                                      \
      for (int kk_ = 0; kk_ < 12; ++kk_) {                                   \
        const short8 b0_ = *(const short8*)&s_cb[BUF][rA][kk_ * 32 + hi * 8];     \
        const short8 b1_ = *(const short8*)&s_cb[BUF][rA + 16][kk_ * 32 + hi * 8];\
        a0_ = __builtin_amdgcn_mfma_f32_16x16x32_bf16(A[kk_], b0_, a0_, 0, 0, 0); \
        a1_ = __builtin_amdgcn_mfma_f32_16x16x32_bf16(A[kk_], b1_, a1_, 0, 0, 0); \
      }                                                                      \
      const int tb_ = (t_ - 4) * 32;                                         \
      const bool m0_ = s_cm[tb_ + rA] != 0;                                  \
      const bool m1_ = s_cm[tb_ + rA + 16] != 0;                             \
      const float ci0_ = s_ci[BUF][rA], ci1_ = s_ci[BUF][rA + 16];           \
      _Pragma("unroll")                                                      \
      for (int r_ = 0; r_ < 4; ++r_) {                                       \
        const float qi_ = s_qi[wave * 16 + hi * 4 + r_];                     \
        const float x0_ = m0_ ? a0_[r_] * (qi_ * ci0_) : -1e9f;              \
        const float x1_ = m1_ ? a1_[r_] * (qi_ * ci1_) : -1e9f;              \
        rm[r_] = fmaxf(rm[r_], fmaxf(x0_, x1_));                             \
      }                                                                      \
    }                                                                        \
  } while (0)

  ISSUE(v0, h0, TBASE(0));
  ISSUE(v1, h1, TBASE(1));

  for (int t = 0; t < NST; t += 2) {
    STAGE(t, v0, h0, 0);
    STAGE(t + 1, v1, h1, 1);
  }

  // ---------------- epilogue ----------------
  // per-half row-max: reduce across the 16 col-lanes, write raw (mask at merge)
#pragma unroll
  for (int r = 0; r < 4; ++r) {
#pragma unroll
    for (int o = 1; o < 16; o <<= 1) rm[r] = fmaxf(rm[r], __shfl_xor(rm[r], o));
  }
  if (rA == 0) {
#pragma unroll
    for (int r = 0; r < 4; ++r)
      ws_rm[(size_t)bid * LQ + wave * 16 + hi * 4 + r] = rm[r];
  }
  __syncthreads();  // all stage-11 LDS reads done before arena reuse

  float* red = (float*)&s_cb[0][0][0];  // [8 waves][2 (q,c)][512] f32 = 32 KB
  *(f4*)&red[(wave * 2 + 0) * 512 + 4 * lane] = pqA;
  *(f4*)&red[(wave * 2 + 0) * 512 + 256 + (hiHalf ? 128 : 0) + 4 * l31] = pqB;
  *(f4*)&red[(wave * 2 + 1) * 512 + 4 * lane] = pcA;
  *(f4*)&red[(wave * 2 + 1) * 512 + 256 + (hiHalf ? 128 : 0) + 4 * l31] = pcB;
  if (lane == 0) { s_cnt[wave] = cq; s_cnt[8 + wave] = cc; }
  __syncthreads();

  if (tid < DIM) {
    float sq = 0.f, sc = 0.f, nq = 0.f, nc = 0.f;
    if (tid < 256) {
#pragma unroll
      for (int w = 0; w < 8; ++w) {
        sq += red[(w * 2 + 0) * 512 + tid];
        sc += red[(w * 2 + 1) * 512 + tid];
      }
    } else {
#pragma unroll
      for (int w = 0; w < 8; ++w) {
        sq += red[(w * 2 + 0) * 512 + tid] + red[(w * 2 + 0) * 512 + tid + 128];
        sc += red[(w * 2 + 1) * 512 + tid] + red[(w * 2 + 1) * 512 + tid + 128];
      }
    }
#pragma unroll
    for (int w = 0; w < 8; ++w) { nq += s_cnt[w]; nc += s_cnt[8 + w]; }
    if (half == 0) pp_q[(size_t)b * DIM + tid] = sq;
    pp_c[(size_t)bid * DIM + tid] = sc;
    if (tid == 0) {
      if (half == 0) nn_q[b] = nq;
      nn_c[bid] = nc;
    }
  }
}

// ============== merge halves -> late; pooled -> 2-row MLP -> emb =============
__global__ __launch_bounds__(DIM)
void merge_mlp(const float* __restrict__ ws_rm, const float* __restrict__ pp_q,
               const float* __restrict__ pp_c, const float* __restrict__ nn_q,
               const float* __restrict__ nn_c, const int* __restrict__ qm,
               const float* __restrict__ W1, const float* __restrict__ b1,
               const float* __restrict__ W2, const float* __restrict__ b2,
               float* __restrict__ late, float* __restrict__ emb) {
  __shared__ float s_q[DIM], s_c[DIM], s_hq[DIM], s_hc[DIM];
  __shared__ float s_red[2][6], s_l[2];
  const int b = blockIdx.x;
  const int d = threadIdx.x;

  if (d < LQ) {
    const float m = fmaxf(ws_rm[(size_t)(2 * b) * LQ + d],
                          ws_rm[(size_t)(2 * b + 1) * LQ + d]);
    float ps = qm[b * LQ + d] ? m : 0.f;
#pragma unroll
    for (int o = 32; o; o >>= 1) ps += __shfl_xor(ps, o);
    if ((d & 63) == 0) s_l[d >> 6] = ps;
  }
  const float nqv = fmaxf(nn_q[b], 1e-9f);
  const float ncv = fmaxf(nn_c[2 * b] + nn_c[2 * b + 1], 1e-9f);
  s_q[d] = pp_q[(size_t)b * DIM + d] / nqv;
  s_c[d] = (pp_c[(size_t)(2 * b) * DIM + d] + pp_c[(size_t)(2 * b + 1) * DIM + d]) / ncv;
  __syncthreads();

  float aq = b1[d], ac = b1[d];
#pragma unroll 8
  for (int k = 0; k < DIM; ++k) {
    const float w = W1[k * DIM + d];
    aq = fmaf(s_q[k], w, aq);
    ac = fmaf(s_c[k], w, ac);
  }
  s_hq[d] = fmaxf(aq, 0.f);
  s_hc[d] = fmaxf(ac, 0.f);
  __syncthreads();
  float pq = b2[d], pc = b2[d];
#pragma unroll 8
  for (int k = 0; k < DIM; ++k) {
    const float w = W2[k * DIM + d];
    pq = fmaf(s_hq[k], w, pq);
    pc = fmaf(s_hc[k], w, pc);
  }
  float q2 = pq * pq, c2 = pc * pc;
#pragma unroll
  for (int o = 32; o; o >>= 1) { q2 += __shfl_xor(q2, o); c2 += __shfl_xor(c2, o); }
  if ((d & 63) == 0) { s_red[0][d >> 6] = q2; s_red[1][d >> 6] = c2; }
  __syncthreads();
  float tq = 0.f, tc = 0.f;
#pragma unroll
  for (int w = 0; w < 6; ++w) { tq += s_red[0][w]; tc += s_red[1][w]; }
  emb[(size_t)b * DIM + d] = pq * (1.0f / fmaxf(sqrtf(tq), 1e-12f));
  emb[(size_t)(NB + b) * DIM + d] = pc * (1.0f / fmaxf(sqrtf(tc), 1e-12f));
  if (d == 0) late[b] = s_l[0] + s_l[1];
}

// ============================== contrast =====================================
__global__ __launch_bounds__(NB)
void contrast_kernel(const float* __restrict__ emb, float* __restrict__ out0) {
  __shared__ float s_q[DIM];
  const int i = blockIdx.x;
  for (int k = threadIdx.x; k < DIM; k += NB) s_q[k] = emb[(size_t)i * DIM + k];
  __syncthreads();
  const float* ce = emb + (size_t)(NB + threadIdx.x) * DIM;
  float acc = 0.f;
#pragma unroll 8
  for (int k = 0; k < DIM; ++k) acc = fmaf(s_q[k], ce[k], acc);
  out0[(size_t)i * NB + threadIdx.x] = acc / 0.07f;
}

// ============================== launch =======================================
extern "C" void kernel_launch(void* const* d_in, const int* in_sizes, int n_in,
                              void* d_out, int out_size, void* d_ws, size_t ws_size,
                              hipStream_t stream) {
  const float* qtok = (const float*)d_in[0];
  const float* ctok = (const float*)d_in[1];
  const int*   qmm  = (const int*)d_in[2];
  const int*   cmm  = (const int*)d_in[3];
  const float* W1   = (const float*)d_in[4];
  const float* b1   = (const float*)d_in[5];
  const float* W2   = (const float*)d_in[6];
  const float* b2   = (const float*)d_in[7];

  float* out0 = (float*)d_out;   // [NB*NB]
  float* late = out0 + NB * NB;  // [NB]

  float* ws_rm = (float*)d_ws;               // [2*NB][LQ]
  float* pp_q  = ws_rm + (size_t)2 * NB * LQ;// [NB][DIM]
  float* pp_c  = pp_q + (size_t)NB * DIM;    // [2*NB][DIM]
  float* nn_q  = pp_c + (size_t)2 * NB * DIM;// [NB]
  float* nn_c  = nn_q + NB;                  // [2*NB]
  float* emb   = nn_c + 2 * NB;              // [2*NB][DIM]

  hipLaunchKernelGGL(fused3, dim3(2 * NB), dim3(512), 0, stream,
                     qtok, ctok, qmm, cmm, ws_rm, pp_q, pp_c, nn_q, nn_c);
  hipLaunchKernelGGL(merge_mlp, dim3(NB), dim3(DIM), 0, stream,
                     ws_rm, pp_q, pp_c, nn_q, nn_c, qmm, W1, b1, W2, b2,
                     late, emb);
  hipLaunchKernelGGL(contrast_kernel, dim3(NB), dim3(NB), 0, stream, emb, out0);
}